// Round 8
// baseline (1471.103 us; speedup 1.0000x reference)
//
#include <hip/hip_runtime.h>
#include <hip/hip_cooperative_groups.h>

namespace cg = cooperative_groups;

// ---------------------------------------------------------------------------
// InterpretableFusion v8 — ONE cooperative kernel, 3 phases, grid.sync between.
//   scores[n,m] = ( x.(G_m l) + x.v_m + l.u_m + c_m )/sqrt(D)
//   G_m = Wq^T Wk_m (bf16, 2 MB, XCD-L2-resident in phase 2).
// v7 -> v8: __launch_bounds__(512,1). v7's (512,2) capped VGPR at 128 and the
// allocator spilled ~270MB stores + ~340MB reloads per pass (WRITE_SIZE 374MB
// vs 104MB real output) inside the inner loops. Cooperative grid is 256
// blocks = 1 block/CU anyway, so the 256-VGPR cap costs zero occupancy.
// Also: merged jh-split GEMM into one pass (kacc[4][4], halves A-reads) with
// manual a/b prefetch so L2-hit G loads hide under MFMAs.
// Phase 1: G (256 blocks, 64x64 tiles) + u,v,c -> out scratch
// Phase 2: persistent sweep of 782 row-tiles: stage X/L (bf16 swizzled LDS),
//          z = G_m l via MFMA, dot with x, reduce, softmax -> weights
// Phase 3: fused = sum_m w_m L_m (streaming; G region dead after sync #2)
// ---------------------------------------------------------------------------

typedef __bf16 bf16x8 __attribute__((ext_vector_type(8)));
typedef __bf16 bf16x4 __attribute__((ext_vector_type(4)));
typedef float  f32x4  __attribute__((ext_vector_type(4)));

#define NTOK 50000
#define DDIM 512
#define NMOD 4
#define BN   64
#define NBLK ((NTOK + BN - 1) / BN)        // 782
#define GRID 256
#define WOFF ((size_t)NTOK * DDIM)         // weights region (float offset)
#define UOFF 600000                        // u[m][d]
#define VOFF 610000                        // v[m][d]
#define COFF 620000                        // c[m]
#define SCALE 0.044194173824159216f        // 1/sqrt(512)

// row stride 1024B (512 bf16); XOR byte bits 4-6 with row&7 (guide §6 G4)
#define SWZ(r, b) ((((r) * 1024) + (b)) ^ (((r) & 7) << 4))

__global__ __launch_bounds__(512, 1) void mono_kernel(
    const float* __restrict__ gnn, const float* __restrict__ lat,
    const float* __restrict__ Wq, const float* __restrict__ bq,
    const float* __restrict__ Wk, const float* __restrict__ bk,
    float* __restrict__ out)
{
    __shared__ __align__(16) char smem[68608];
    const int tid = threadIdx.x;
    const int bid = blockIdx.x;
    cg::grid_group grid = cg::this_grid();

    // ================= phase 1: G = Wq^T Wk_m  (+ u, v, c) =================
    {
        float* ldsQ = (float*)smem;            // [64][64]
        float* ldsK = (float*)(smem + 16384);  // [64][64]
        const int m = bid >> 6, ib = bid & 63, dblk = ib >> 3, dpb = ib & 7;
        const int dl = tid >> 3, c8 = tid & 7; // row-in-tile, col-group(8)
        f32x4 ac0 = {0.f,0.f,0.f,0.f}, ac1 = {0.f,0.f,0.f,0.f};
        for (int e0 = 0; e0 < DDIM; e0 += 64) {
            __syncthreads();
            #pragma unroll
            for (int it = 0; it < 2; ++it) {
                int idx = it * 512 + tid, e = idx >> 4, c4 = idx & 15;
                *(f32x4*)&ldsQ[e * 64 + c4 * 4] =
                    *(const f32x4*)&Wq[(size_t)(e0 + e) * DDIM + dblk * 64 + c4 * 4];
                *(f32x4*)&ldsK[e * 64 + c4 * 4] =
                    *(const f32x4*)&Wk[((size_t)m * DDIM + e0 + e) * DDIM + dpb * 64 + c4 * 4];
            }
            __syncthreads();
            for (int e = 0; e < 64; ++e) {
                float wq = ldsQ[e * 64 + dl];
                const f32x4* wk = (const f32x4*)&ldsK[e * 64 + c8 * 8];
                ac0 += wq * wk[0];
                ac1 += wq * wk[1];
            }
        }
        __bf16* Gb = (__bf16*)out;
        bf16x8 o;
        o[0]=(__bf16)ac0[0]; o[1]=(__bf16)ac0[1]; o[2]=(__bf16)ac0[2]; o[3]=(__bf16)ac0[3];
        o[4]=(__bf16)ac1[0]; o[5]=(__bf16)ac1[1]; o[6]=(__bf16)ac1[2]; o[7]=(__bf16)ac1[3];
        *(bf16x8*)(Gb + ((size_t)m * DDIM + dblk * 64 + dl) * DDIM + dpb * 64 + c8 * 8) = o;

        if (bid < 32) {                        // u, v, c on 32 blocks
            __syncthreads();                   // LDS G-reads done; reuse buffer
            float* up = ldsQ;                  // [4][64]
            float* vp = ldsQ + 256;            // [4][64]
            const int m2 = bid >> 3, dc = bid & 7;
            if (tid < 256) {
                const int dl2 = tid & 63, eg = tid >> 6;
                const int d = dc * 64 + dl2;
                float us = 0.f, vs = 0.f;
                #pragma unroll 4
                for (int e = eg * 128; e < eg * 128 + 128; ++e) {
                    us += Wk[((size_t)m2 * DDIM + e) * DDIM + d] * bq[e];
                    vs += Wq[(size_t)e * DDIM + d] * bk[m2 * DDIM + e];
                }
                up[eg * 64 + dl2] = us; vp[eg * 64 + dl2] = vs;
            }
            __syncthreads();
            if (tid < 64) {
                const int d = dc * 64 + tid;
                out[UOFF + m2 * DDIM + d] = up[tid] + up[64+tid] + up[128+tid] + up[192+tid];
                out[VOFF + m2 * DDIM + d] = vp[tid] + vp[64+tid] + vp[128+tid] + vp[192+tid];
                if (dc == 0) {
                    float cp = 0.f;
                    #pragma unroll
                    for (int i = 0; i < 8; ++i)
                        cp += bq[tid * 8 + i] * bk[m2 * DDIM + tid * 8 + i];
                    #pragma unroll
                    for (int msk = 1; msk < 64; msk <<= 1)
                        cp += __shfl_xor(cp, msk, 64);
                    if (tid == 0) out[COFF + m2] = cp;
                }
            }
        }
    }
    grid.sync();   // G/u/v/c visible device-wide

    // ================= phase 2: scores -> softmax -> weights =================
    {
        __bf16* tile  = (__bf16*)smem;             // 64 KiB
        float* s_part = (float*)(smem + 65536);    // [8][64]
        float* s_all  = (float*)(smem + 67584);    // [64][4]
        const __bf16* Gb = (const __bf16*)out;
        const int lane = tid & 63, w = tid >> 6;
        const int g = (lane >> 4) & 3, c = lane & 15;

        for (int t = bid; t < NBLK; t += GRID) {
            const int row0 = t * BN;
            const int vrows = (NTOK - row0 < BN) ? (NTOK - row0) : BN;

            auto stage = [&](const float* src, int rsF) {
                #pragma unroll
                for (int bat = 0; bat < 2; ++bat) {
                    f32x4 tmp[8];
                    #pragma unroll
                    for (int i = 0; i < 8; ++i) {
                        int f4 = (bat * 8 + i) * 512 + tid, r = f4 >> 7, c4 = f4 & 127;
                        tmp[i] = (r < vrows)
                            ? __builtin_nontemporal_load(
                                  (const f32x4*)(src + (size_t)r * rsF + c4 * 4))
                            : (f32x4){0.f, 0.f, 0.f, 0.f};
                    }
                    #pragma unroll
                    for (int i = 0; i < 8; ++i) {
                        int f4 = (bat * 8 + i) * 512 + tid, r = f4 >> 7, c4 = f4 & 127;
                        bf16x4 o;
                        o[0] = (__bf16)tmp[i][0]; o[1] = (__bf16)tmp[i][1];
                        o[2] = (__bf16)tmp[i][2]; o[3] = (__bf16)tmp[i][3];
                        *(bf16x4*)((char*)tile + SWZ(r, c4 * 8)) = o;
                    }
                }
            };

            // X tile -> xbf regs (rows rt*16+g*4+reg, cols w*64+j*16+c)
            stage(gnn + (size_t)row0 * DDIM, DDIM);
            __syncthreads();
            bf16x4 xbf[4][4];
            #pragma unroll
            for (int rt = 0; rt < 4; ++rt)
                #pragma unroll
                for (int j = 0; j < 4; ++j) {
                    bf16x4 tq;
                    #pragma unroll
                    for (int reg = 0; reg < 4; ++reg) {
                        int r = rt * 16 + g * 4 + reg, col = w * 64 + j * 16 + c;
                        tq[reg] = *(const __bf16*)((const char*)tile + SWZ(r, col * 2));
                    }
                    xbf[rt][j] = tq;
                }

            for (int m = 0; m < NMOD; ++m) {
                __syncthreads();
                stage(lat + ((size_t)row0 * NMOD + m) * DDIM, NMOD * DDIM);
                __syncthreads();

                float u4[4], v4[4];
                #pragma unroll
                for (int j = 0; j < 4; ++j) {
                    int col = w * 64 + j * 16 + c;
                    u4[j] = out[UOFF + m * DDIM + col];
                    v4[j] = out[VOFF + m * DDIM + col];
                }
                float p[4][4];
                #pragma unroll
                for (int rt = 0; rt < 4; ++rt)
                    #pragma unroll
                    for (int reg = 0; reg < 4; ++reg) {
                        int r = rt * 16 + g * 4 + reg;
                        float tacc = 0.f;
                        #pragma unroll
                        for (int j = 0; j < 4; ++j) {
                            int col = w * 64 + j * 16 + c;
                            float lv = (float)*(const __bf16*)((const char*)tile +
                                                               SWZ(r, col * 2));
                            tacc += (float)xbf[rt][j][reg] * v4[j] + lv * u4[j];
                        }
                        p[rt][reg] = tacc;
                    }

                // z = G_m l via MFMA, single pass, software-pipelined a/b loads
                f32x4 kacc[4][4];
                #pragma unroll
                for (int rt = 0; rt < 4; ++rt)
                    #pragma unroll
                    for (int j = 0; j < 4; ++j)
                        kacc[rt][j] = (f32x4){0.f, 0.f, 0.f, 0.f};

                const __bf16* Gm = Gb + (size_t)m * DDIM * DDIM;
                auto LDAB = [&](int k0, bf16x8* a, bf16x8* b) {
                    const int kb = k0 * 2 + g * 16;
                    #pragma unroll
                    for (int rt = 0; rt < 4; ++rt)
                        a[rt] = *(const bf16x8*)((const char*)tile +
                                                 SWZ(rt * 16 + c, kb));
                    #pragma unroll
                    for (int j = 0; j < 4; ++j)
                        b[j] = *(const bf16x8*)(Gm + (size_t)(w * 64 + j * 16 + c) * DDIM
                                                + k0 + g * 8);
                };
                bf16x8 a0[4], b0[4];
                LDAB(0, a0, b0);
                #pragma unroll 4
                for (int k0 = 0; k0 < DDIM; k0 += 32) {
                    bf16x8 a1[4], b1[4];
                    if (k0 + 32 < DDIM) LDAB(k0 + 32, a1, b1);
                    #pragma unroll
                    for (int rt = 0; rt < 4; ++rt)
                        #pragma unroll
                        for (int j = 0; j < 4; ++j)
                            kacc[rt][j] = __builtin_amdgcn_mfma_f32_16x16x32_bf16(
                                a0[rt], b0[j], kacc[rt][j], 0, 0, 0);
                    #pragma unroll
                    for (int i = 0; i < 4; ++i) { a0[i] = a1[i]; b0[i] = b1[i]; }
                }
                #pragma unroll
                for (int rt = 0; rt < 4; ++rt)
                    #pragma unroll
                    for (int reg = 0; reg < 4; ++reg) {
                        float tacc = p[rt][reg];
                        #pragma unroll
                        for (int j = 0; j < 4; ++j)
                            tacc += (float)xbf[rt][j][reg] * kacc[rt][j][reg];
                        p[rt][reg] = tacc;
                    }

                // reduce over 16 c-lanes, then across 8 waves via LDS
                #pragma unroll
                for (int msk = 1; msk < 16; msk <<= 1)
                    #pragma unroll
                    for (int rt = 0; rt < 4; ++rt)
                        #pragma unroll
                        for (int reg = 0; reg < 4; ++reg)
                            p[rt][reg] += __shfl_xor(p[rt][reg], msk, 64);
                if (c == 0) {
                    #pragma unroll
                    for (int rt = 0; rt < 4; ++rt)
                        #pragma unroll
                        for (int reg = 0; reg < 4; ++reg)
                            s_part[w * 64 + rt * 16 + g * 4 + reg] = p[rt][reg];
                }
                __syncthreads();
                if (tid < BN) {
                    float s = 0.f;
                    #pragma unroll
                    for (int ww = 0; ww < 8; ++ww) s += s_part[ww * 64 + tid];
                    s_all[tid * 4 + m] = s + out[COFF + m];
                }
            }

            if (tid < BN && row0 + tid < NTOK) {
                float e0 = __expf(s_all[tid*4+0] * SCALE), e1 = __expf(s_all[tid*4+1] * SCALE),
                      e2 = __expf(s_all[tid*4+2] * SCALE), e3 = __expf(s_all[tid*4+3] * SCALE);
                float iz = 1.f / (e0 + e1 + e2 + e3);
                f32x4 wv = {e0 * iz, e1 * iz, e2 * iz, e3 * iz};
                *(f32x4*)(out + WOFF + (size_t)(row0 + tid) * 4) = wv;   // regular store
            }
        }
    }
    grid.sync();   // weights visible; G region now dead

    // ================= phase 3: fused = sum_m w_m L_m =================
    {
        const int rl = tid >> 3, k2 = tid & 7;     // 64 rows/iter, 8 thr/row
        const int base = bid * 196;                // 256*196 = 50176 >= 50000
        #pragma unroll
        for (int ii = 0; ii < 4; ++ii) {
            const int rr = ii * 64 + rl;
            const int n = base + rr;
            if (rr < 196 && n < NTOK) {
                f32x4 w4 = *(const f32x4*)(out + WOFF + (size_t)n * 4);
                const float* lp0 = lat + (size_t)n * NMOD * DDIM + k2 * 64;
                float* op = out + (size_t)n * DDIM + k2 * 64;
                #pragma unroll
                for (int cc = 0; cc < 4; ++cc) {
                    f32x4 ac[4];
                    #pragma unroll
                    for (int i = 0; i < 4; ++i) ac[i] = (f32x4){0.f, 0.f, 0.f, 0.f};
                    #pragma unroll
                    for (int m = 0; m < NMOD; ++m) {
                        const float* lp = lp0 + m * DDIM + cc * 16;
                        #pragma unroll
                        for (int i = 0; i < 4; ++i) {
                            f32x4 v = __builtin_nontemporal_load((const f32x4*)(lp + i * 4));
                            ac[i] += w4[m] * v;
                        }
                    }
                    #pragma unroll
                    for (int i = 0; i < 4; ++i)
                        __builtin_nontemporal_store(ac[i], (f32x4*)(op + cc * 16 + i * 4));
                }
            }
        }
    }
}

extern "C" void kernel_launch(void* const* d_in, const int* in_sizes, int n_in,
                              void* d_out, int out_size, void* d_ws, size_t ws_size,
                              hipStream_t stream)
{
    const float* gnn = (const float*)d_in[0];   // [N, D]
    const float* lat = (const float*)d_in[1];   // [N, M, D]
    const float* Wq  = (const float*)d_in[2];   // [D, D]
    const float* bq  = (const float*)d_in[3];   // [D]
    const float* Wk  = (const float*)d_in[4];   // [M, D, D]
    const float* bk  = (const float*)d_in[5];   // [M, D]
    float* out = (float*)d_out;                 // fused [N,D] ++ weights [N,M]

    void* args[] = { (void*)&gnn, (void*)&lat, (void*)&Wq, (void*)&bq,
                     (void*)&Wk, (void*)&bk, (void*)&out };
    hipLaunchCooperativeKernel((const void*)mono_kernel, dim3(GRID), dim3(512),
                               args, 0, stream);
}

// Round 9
// 651.514 us; speedup vs baseline: 2.2580x; 2.2580x over previous
//
#include <hip/hip_runtime.h>
#include <hip/hip_cooperative_groups.h>

namespace cg = cooperative_groups;

// ---------------------------------------------------------------------------
// InterpretableFusion v9 — ONE cooperative kernel, 3 phases, grid.sync between.
//   scores[n,m] = ( x.(G_m l) + x.v_m + l.u_m + c_m )/sqrt(D)
//   G_m = Wq^T Wk_m (bf16, 2 MB, L2-resident in phase 2).
// v8 -> v9: the compiler pins this kernel at 128 arch-VGPRs regardless of
// launch_bounds (observed 128 at (512,1)+(512,2), 64 at (512,4)/(1024,1));
// anything live above that spills (v8: 670 MB of scratch traffic). So:
// design UNDER the cap: 4 single-j GEMM passes (kacc 16 + b 4 + a 16 regs,
// sched_barrier(0) between passes), 4-deep staging batches, bias fast-path
// (u,v,c == 0 for these inputs; flags computed in phase 1, general-correct).
// Plus: GRID=512 -> 2 blocks/CU (LDS 67KB, 128x16 VGPR = exact fit) for 2x
// latency hiding, and a fully slot-coalesced phase 3.
// ---------------------------------------------------------------------------

typedef __bf16 bf16x8 __attribute__((ext_vector_type(8)));
typedef __bf16 bf16x4 __attribute__((ext_vector_type(4)));
typedef float  f32x4  __attribute__((ext_vector_type(4)));

#define NTOK 50000
#define DDIM 512
#define NMOD 4
#define BN   64
#define NBLK ((NTOK + BN - 1) / BN)        // 782
#define WOFF ((size_t)NTOK * DDIM)         // weights region (float offset)
#define UOFF 600000                        // u[m][d]
#define VOFF 610000                        // v[m][d]
#define COFF 620000                        // c[m]
#define FOFF 620004                        // 32 bias-nonzero flags
#define SCALE 0.044194173824159216f        // 1/sqrt(512)

// row stride 1024B (512 bf16); XOR byte bits 4-6 with row&7 (guide §6 G4)
#define SWZ(r, b) ((((r) * 1024) + (b)) ^ (((r) & 7) << 4))

__global__ __launch_bounds__(512, 2) void mono_kernel(
    const float* __restrict__ gnn, const float* __restrict__ lat,
    const float* __restrict__ Wq, const float* __restrict__ bq,
    const float* __restrict__ Wk, const float* __restrict__ bk,
    float* __restrict__ out)
{
    __shared__ __align__(16) char smem[68608];
    const int tid = threadIdx.x;
    const int bid = blockIdx.x;
    const int ngrid = gridDim.x;
    cg::grid_group gg = cg::this_grid();

    // ========== phase 1: G = Wq^T Wk_m (512 subtiles of 64x32) + u,v,c ======
    {
        float* ldsQ = (float*)smem;            // [64][64] fp32
        float* ldsK = (float*)(smem + 16384);  // [64][32] fp32
        for (int gb = bid; gb < 512; gb += ngrid) {
            const int m = gb >> 7, ib = gb & 127, dblk = ib >> 4, dpb = ib & 15;
            const int dl = tid >> 3, c8 = tid & 7;
            f32x4 ac = {0.f, 0.f, 0.f, 0.f};
            for (int e0 = 0; e0 < DDIM; e0 += 64) {
                __syncthreads();
                #pragma unroll
                for (int it = 0; it < 2; ++it) {
                    int idx = it * 512 + tid, e = idx >> 4, c4 = idx & 15;
                    *(f32x4*)&ldsQ[e * 64 + c4 * 4] =
                        *(const f32x4*)&Wq[(size_t)(e0 + e) * DDIM + dblk * 64 + c4 * 4];
                }
                {
                    int e = tid >> 3, c4 = tid & 7;
                    *(f32x4*)&ldsK[e * 32 + c4 * 4] =
                        *(const f32x4*)&Wk[((size_t)m * DDIM + e0 + e) * DDIM + dpb * 32 + c4 * 4];
                }
                __syncthreads();
                for (int e = 0; e < 64; ++e) {
                    float wq = ldsQ[e * 64 + dl];
                    ac += wq * *(const f32x4*)&ldsK[e * 32 + c8 * 4];
                }
            }
            __bf16* Gw = (__bf16*)out;
            bf16x4 o;
            o[0] = (__bf16)ac[0]; o[1] = (__bf16)ac[1];
            o[2] = (__bf16)ac[2]; o[3] = (__bf16)ac[3];
            *(bf16x4*)(Gw + ((size_t)m * DDIM + dblk * 64 + dl) * DDIM
                       + dpb * 32 + c8 * 4) = o;
        }

        if (bid < 32) {                        // u, v, c + bias flags
            __syncthreads();                   // own block's G reads done
            float* up = (float*)smem;          // [4][64]
            float* vp = (float*)smem + 256;    // [4][64]
            const int m2 = bid >> 3, dc = bid & 7;
            if (tid < 256) {
                const int dl2 = tid & 63, eg = tid >> 6;
                const int d = dc * 64 + dl2;
                float us = 0.f, vs = 0.f;
                #pragma unroll 4
                for (int e = eg * 128; e < eg * 128 + 128; ++e) {
                    us += Wk[((size_t)m2 * DDIM + e) * DDIM + d] * bq[e];
                    vs += Wq[(size_t)e * DDIM + d] * bk[m2 * DDIM + e];
                }
                up[eg * 64 + dl2] = us; vp[eg * 64 + dl2] = vs;
            }
            __syncthreads();
            if (tid < 64) {
                const int d = dc * 64 + tid;
                float uu = up[tid] + up[64+tid] + up[128+tid] + up[192+tid];
                float vv = vp[tid] + vp[64+tid] + vp[128+tid] + vp[192+tid];
                out[UOFF + m2 * DDIM + d] = uu;
                out[VOFF + m2 * DDIM + d] = vv;
                float cp = 0.f;
                if (dc == 0) {
                    #pragma unroll
                    for (int i = 0; i < 8; ++i)
                        cp += bq[tid * 8 + i] * bk[m2 * DDIM + tid * 8 + i];
                    #pragma unroll
                    for (int msk = 1; msk < 64; msk <<= 1)
                        cp += __shfl_xor(cp, msk, 64);
                    if (tid == 0) out[COFF + m2] = cp;
                }
                unsigned long long anyb =
                    __ballot((uu != 0.f) || (vv != 0.f) || (cp != 0.f));
                if (tid == 0) out[FOFF + bid] = anyb ? 1.f : 0.f;  // always written
            }
        }
    }
    gg.sync();   // G/u/v/c/flags visible device-wide

    // ========== phase 2: scores -> softmax -> weights ==========
    {
        __bf16* tile  = (__bf16*)smem;             // 64 KiB (X once, then L_m)
        float* s_part = (float*)(smem + 65536);    // [8][64]
        float* s_all  = (float*)(smem + 67584);    // [64][4]
        const __bf16* Gb = (const __bf16*)out;
        const int lane = tid & 63, w = tid >> 6;
        const int g = (lane >> 4) & 3, c = lane & 15;

        bool bias = false;
        for (int i2 = 0; i2 < 32; ++i2) bias |= (out[FOFF + i2] != 0.f);

        for (int t = bid; t < NBLK; t += ngrid) {
            const int row0 = t * BN;
            const int vrows = (NTOK - row0 < BN) ? (NTOK - row0) : BN;

            auto stage = [&](const float* src, int rsF) {
                #pragma unroll
                for (int bat = 0; bat < 4; ++bat) {
                    f32x4 tmp[4];
                    #pragma unroll
                    for (int i = 0; i < 4; ++i) {
                        int f4 = (bat * 4 + i) * 512 + tid, r = f4 >> 7, c4 = f4 & 127;
                        tmp[i] = (r < vrows)
                            ? __builtin_nontemporal_load(
                                  (const f32x4*)(src + (size_t)r * rsF + c4 * 4))
                            : (f32x4){0.f, 0.f, 0.f, 0.f};
                    }
                    #pragma unroll
                    for (int i = 0; i < 4; ++i) {
                        int f4 = (bat * 4 + i) * 512 + tid, r = f4 >> 7, c4 = f4 & 127;
                        bf16x4 o;
                        o[0] = (__bf16)tmp[i][0]; o[1] = (__bf16)tmp[i][1];
                        o[2] = (__bf16)tmp[i][2]; o[3] = (__bf16)tmp[i][3];
                        *(bf16x4*)((char*)tile + SWZ(r, c4 * 8)) = o;
                    }
                }
            };

            // X tile -> xbf regs (rows rt*16+g*4+reg, cols w*64+j*16+c)
            stage(gnn + (size_t)row0 * DDIM, DDIM);
            __syncthreads();
            bf16x4 xbf[4][4];
            #pragma unroll
            for (int rt = 0; rt < 4; ++rt)
                #pragma unroll
                for (int j = 0; j < 4; ++j) {
                    bf16x4 tq;
                    #pragma unroll
                    for (int reg = 0; reg < 4; ++reg) {
                        int r = rt * 16 + g * 4 + reg, col = w * 64 + j * 16 + c;
                        tq[reg] = *(const __bf16*)((const char*)tile + SWZ(r, col * 2));
                    }
                    xbf[rt][j] = tq;
                }

            for (int m = 0; m < NMOD; ++m) {
                __syncthreads();   // xbf-extract / prev-m tile & s_part reads done
                stage(lat + ((size_t)row0 * NMOD + m) * DDIM, NMOD * DDIM);
                __syncthreads();

                float p[4][4];
                if (bias) {   // general path (u,v != 0); skipped for these inputs
                    float u4[4], v4[4];
                    #pragma unroll
                    for (int j = 0; j < 4; ++j) {
                        int col = w * 64 + j * 16 + c;
                        u4[j] = out[UOFF + m * DDIM + col];
                        v4[j] = out[VOFF + m * DDIM + col];
                    }
                    #pragma unroll
                    for (int rt = 0; rt < 4; ++rt)
                        #pragma unroll
                        for (int reg = 0; reg < 4; ++reg) {
                            int r = rt * 16 + g * 4 + reg;
                            float tacc = 0.f;
                            #pragma unroll
                            for (int j = 0; j < 4; ++j) {
                                int col = w * 64 + j * 16 + c;
                                float lv = (float)*(const __bf16*)((const char*)tile +
                                                                   SWZ(r, col * 2));
                                tacc += (float)xbf[rt][j][reg] * v4[j] + lv * u4[j];
                            }
                            p[rt][reg] = tacc;
                        }
                } else {
                    #pragma unroll
                    for (int rt = 0; rt < 4; ++rt)
                        #pragma unroll
                        for (int reg = 0; reg < 4; ++reg)
                            p[rt][reg] = 0.f;
                }

                // z = G_m l via MFMA: 4 single-j passes, dot folded per pass.
                // Keeps live regs ~(xbf32 + p16 + kacc16 + a16 + b4) < 128 cap.
                const __bf16* Gm = Gb + (size_t)m * DDIM * DDIM;
                #pragma unroll
                for (int jp = 0; jp < 4; ++jp) {
                    f32x4 kacc[4];
                    #pragma unroll
                    for (int rt = 0; rt < 4; ++rt)
                        kacc[rt] = (f32x4){0.f, 0.f, 0.f, 0.f};
                    const __bf16* gp = Gm + (size_t)(w * 64 + jp * 16 + c) * DDIM + g * 8;
                    for (int k0 = 0; k0 < DDIM; k0 += 32) {
                        bf16x8 b = *(const bf16x8*)(gp + k0);
                        bf16x8 a[4];
                        const int kb = k0 * 2 + g * 16;
                        #pragma unroll
                        for (int rt = 0; rt < 4; ++rt)
                            a[rt] = *(const bf16x8*)((const char*)tile +
                                                     SWZ(rt * 16 + c, kb));
                        #pragma unroll
                        for (int rt = 0; rt < 4; ++rt)
                            kacc[rt] = __builtin_amdgcn_mfma_f32_16x16x32_bf16(
                                a[rt], b, kacc[rt], 0, 0, 0);
                    }
                    #pragma unroll
                    for (int rt = 0; rt < 4; ++rt)
                        #pragma unroll
                        for (int reg = 0; reg < 4; ++reg)
                            p[rt][reg] += (float)xbf[rt][jp][reg] * kacc[rt][reg];
                    __builtin_amdgcn_sched_barrier(0);  // no cross-pass fusion
                }

                // reduce over 16 c-lanes, then across 8 waves via LDS
                #pragma unroll
                for (int msk = 1; msk < 16; msk <<= 1)
                    #pragma unroll
                    for (int rt = 0; rt < 4; ++rt)
                        #pragma unroll
                        for (int reg = 0; reg < 4; ++reg)
                            p[rt][reg] += __shfl_xor(p[rt][reg], msk, 64);
                if (c == 0) {
                    #pragma unroll
                    for (int rt = 0; rt < 4; ++rt)
                        #pragma unroll
                        for (int reg = 0; reg < 4; ++reg)
                            s_part[w * 64 + rt * 16 + g * 4 + reg] = p[rt][reg];
                }
                __syncthreads();
                if (tid < BN) {
                    float s = 0.f;
                    #pragma unroll
                    for (int ww = 0; ww < 8; ++ww) s += s_part[ww * 64 + tid];
                    s_all[tid * 4 + m] = s + out[COFF + m];
                }
            }

            if (tid < BN && row0 + tid < NTOK) {
                float e0 = __expf(s_all[tid*4+0] * SCALE), e1 = __expf(s_all[tid*4+1] * SCALE),
                      e2 = __expf(s_all[tid*4+2] * SCALE), e3 = __expf(s_all[tid*4+3] * SCALE);
                float iz = 1.f / (e0 + e1 + e2 + e3);
                f32x4 wv = {e0 * iz, e1 * iz, e2 * iz, e3 * iz};
                *(f32x4*)(out + WOFF + (size_t)(row0 + tid) * 4) = wv;
            }
        }
    }
    gg.sync();   // weights visible; G/u/v/c/flags region now dead

    // ========== phase 3: fused = sum_m w_m L_m (slot-coalesced) ==========
    {
        const long total4 = (long)NTOK * (DDIM / 4);          // 6,400,000
        for (long idx = (long)bid * 512 + tid; idx < total4;
             idx += (long)ngrid * 512) {
            const int row = (int)(idx >> 7), c4 = (int)(idx & 127);
            f32x4 w4 = *(const f32x4*)(out + WOFF + (size_t)row * 4);
            f32x4 acc = {0.f, 0.f, 0.f, 0.f};
            #pragma unroll
            for (int m = 0; m < NMOD; ++m) {
                f32x4 v = __builtin_nontemporal_load(
                    (const f32x4*)(lat + ((size_t)row * NMOD + m) * DDIM + c4 * 4));
                acc += w4[m] * v;
            }
            __builtin_nontemporal_store(acc, (f32x4*)(out + (size_t)idx * 4));
        }
    }
}

extern "C" void kernel_launch(void* const* d_in, const int* in_sizes, int n_in,
                              void* d_out, int out_size, void* d_ws, size_t ws_size,
                              hipStream_t stream)
{
    const float* gnn = (const float*)d_in[0];   // [N, D]
    const float* lat = (const float*)d_in[1];   // [N, M, D]
    const float* Wq  = (const float*)d_in[2];   // [D, D]
    const float* bq  = (const float*)d_in[3];   // [D]
    const float* Wk  = (const float*)d_in[4];   // [M, D, D]
    const float* bk  = (const float*)d_in[5];   // [M, D]
    float* out = (float*)d_out;                 // fused [N,D] ++ weights [N,M]

    int maxb = 0;
    hipError_t oe = hipOccupancyMaxActiveBlocksPerMultiprocessor(
        &maxb, mono_kernel, 512, 0);
    const int ngrid = (oe == hipSuccess && maxb >= 2) ? 512 : 256;

    void* args[] = { (void*)&gnn, (void*)&lat, (void*)&Wq, (void*)&bq,
                     (void*)&Wk, (void*)&bk, (void*)&out };
    hipLaunchCooperativeKernel((const void*)mono_kernel, dim3(ngrid), dim3(512),
                               args, 0, stream);
}